// Round 1
// baseline (134.021 us; speedup 1.0000x reference)
//
#include <hip/hip_runtime.h>

// Problem constants (from reference)
#define NPIX   786432      // C*H*W = 3*512*512
#define NSP    55050       // num scattered pixels per sample
#define BATCH  64

// Kernel 1: vectorized copy + clip (clip is identity for uniform[0,1] input,
// applied anyway to match reference semantics exactly).
__global__ void copy_clip_kernel(const float4* __restrict__ in,
                                 float4* __restrict__ out, int n4) {
    int stride = gridDim.x * blockDim.x;
    for (int i = blockIdx.x * blockDim.x + threadIdx.x; i < n4; i += stride) {
        float4 v = in[i];
        v.x = fminf(fmaxf(v.x, 0.0f), 1.0f);
        v.y = fminf(fmaxf(v.y, 0.0f), 1.0f);
        v.z = fminf(fmaxf(v.z, 0.0f), 1.0f);
        v.w = fminf(fmaxf(v.w, 0.0f), 1.0f);
        out[i] = v;
    }
}

// Kernel 2: scatter salt/pepper. indices are per-sample permutation prefixes,
// so no duplicate targets within a sample -> no write conflicts.
__global__ void scatter_kernel(const int* __restrict__ indices,
                               const int* __restrict__ num_salt,
                               float* __restrict__ out) {
    int b = blockIdx.y;
    int j = blockIdx.x * blockDim.x + threadIdx.x;
    if (j >= NSP) return;
    int idx = indices[b * NSP + j];
    float v = (j < num_salt[b]) ? 1.0f : 0.0f;
    out[(size_t)b * NPIX + idx] = v;
}

extern "C" void kernel_launch(void* const* d_in, const int* in_sizes, int n_in,
                              void* d_out, int out_size, void* d_ws, size_t ws_size,
                              hipStream_t stream) {
    const float* x        = (const float*)d_in[0];
    const int*   indices  = (const int*)d_in[1];
    const int*   num_salt = (const int*)d_in[2];
    float*       out      = (float*)d_out;

    // 1) bulk copy+clip, float4-vectorized, grid-stride
    int n4 = out_size / 4;  // 12,582,912 float4s
    copy_clip_kernel<<<2048, 256, 0, stream>>>(
        (const float4*)x, (float4*)out, n4);

    // 2) scatter (must follow the copy; same stream serializes)
    dim3 sgrid((NSP + 255) / 256, BATCH);
    scatter_kernel<<<sgrid, 256, 0, stream>>>(indices, num_salt, out);
}

// Round 2
// 115.247 us; speedup vs baseline: 1.1629x; 1.1629x over previous
//
#include <hip/hip_runtime.h>

// Problem constants (from reference)
#define NPIX   786432      // C*H*W = 3*512*512
#define NSP    55050       // num scattered pixels per sample
#define BATCH  64

typedef float f32x4 __attribute__((ext_vector_type(4)));

// Kernel 1: vectorized copy + clip.
// Input is read ONCE -> use non-temporal loads (nt flag) so the 201 MB input
// stream does not evict the 201 MB output from the 256 MB L3. Keeping the
// output L3-resident makes the following scatter's random writes cheap
// (dirty-line hits instead of HBM read-modify-write).
__global__ __launch_bounds__(256) void copy_clip_kernel(
    const f32x4* __restrict__ in, f32x4* __restrict__ out, int n4) {
    int stride = gridDim.x * blockDim.x;
    for (int i = blockIdx.x * blockDim.x + threadIdx.x; i < n4; i += stride) {
        f32x4 v = __builtin_nontemporal_load(in + i);
        v.x = fminf(fmaxf(v.x, 0.0f), 1.0f);
        v.y = fminf(fmaxf(v.y, 0.0f), 1.0f);
        v.z = fminf(fmaxf(v.z, 0.0f), 1.0f);
        v.w = fminf(fmaxf(v.w, 0.0f), 1.0f);
        out[i] = v;  // regular store: allocate in L2/L3, stays resident
    }
}

// Kernel 2: scatter salt/pepper. indices are per-sample permutation prefixes,
// so no duplicate targets within a sample -> no write conflicts.
__global__ __launch_bounds__(256) void scatter_kernel(
    const int* __restrict__ indices, const int* __restrict__ num_salt,
    float* __restrict__ out) {
    int b = blockIdx.y;
    int j = blockIdx.x * blockDim.x + threadIdx.x;
    if (j >= NSP) return;
    int idx = indices[b * NSP + j];         // coalesced
    float v = (j < num_salt[b]) ? 1.0f : 0.0f;
    out[(size_t)b * NPIX + idx] = v;        // random, should hit L3 dirty lines
}

extern "C" void kernel_launch(void* const* d_in, const int* in_sizes, int n_in,
                              void* d_out, int out_size, void* d_ws, size_t ws_size,
                              hipStream_t stream) {
    const float* x        = (const float*)d_in[0];
    const int*   indices  = (const int*)d_in[1];
    const int*   num_salt = (const int*)d_in[2];
    float*       out      = (float*)d_out;

    // 1) bulk copy+clip, float4-vectorized, grid-stride, nt input loads
    int n4 = out_size / 4;  // 12,582,912 float4s
    copy_clip_kernel<<<2048, 256, 0, stream>>>(
        (const f32x4*)x, (f32x4*)out, n4);

    // 2) scatter (same stream serializes after the copy)
    dim3 sgrid((NSP + 255) / 256, BATCH);
    scatter_kernel<<<sgrid, 256, 0, stream>>>(indices, num_salt, out);
}